// Round 5
// baseline (439.031 us; speedup 1.0000x reference)
//
#include <hip/hip_runtime.h>

#define T_TOKENS 2048
#define DIM 1024
#define ISZ 2048
#define NEXP 8
#define NPAIRS (T_TOKENS * 2)
#define CAP (NPAIRS + 256)
#define MAXTILES 48
#define BK 32
#define BM 128

typedef __attribute__((ext_vector_type(8))) short bf16x8;
typedef __attribute__((ext_vector_type(4))) float f32x4;

constexpr int GU_NSTEP  = DIM / BK;          // 32
constexpr int DN_NSTEP  = ISZ / BK;          // 64
constexpr int A_BYTES   = BM * 64;           // 8192: A tile 128 rows x 64B (BK=32 bf16)
constexpr int B_STRIDE  = 80;                // padded row stride (64B data + 16B pad)
constexpr int B_BYTES   = 64 * B_STRIDE;     // 5120 per B tensor tile
constexpr int GU_BUFB   = A_BYTES + 2 * B_BYTES;   // 18432
constexpr int DN_BUFB   = A_BYTES + B_BYTES;       // 13312

// ---------------- ws layout ----------------
constexpr size_t OFF_COUNTS  = 0;
constexpr size_t OFF_CURSOR  = 32;
constexpr size_t OFF_OFFSETS = 64;
constexpr size_t OFF_NTILES  = 96;
constexpr size_t OFF_TILE_E  = 128;
constexpr size_t OFF_TILE_R0 = OFF_TILE_E  + MAXTILES * 4;
constexpr size_t OFF_TILE_NR = OFF_TILE_R0 + MAXTILES * 4;   // end < 1024
constexpr size_t OFF_TOPK_I = 1024;
constexpr size_t OFF_TOPK_W = OFF_TOPK_I + (size_t)NPAIRS * 4;
constexpr size_t OFF_ROW_T  = OFF_TOPK_W + (size_t)NPAIRS * 4;
constexpr size_t OFF_ROW_W  = OFF_ROW_T + (size_t)CAP * 4;
constexpr size_t OFF_TSLOT  = OFF_ROW_W + (size_t)CAP * 4;
constexpr size_t OFF_XG     = (OFF_TSLOT + (size_t)NPAIRS * 4 + 255) & ~(size_t)255;
constexpr size_t OFF_H      = OFF_XG + (size_t)CAP * DIM * 2;
constexpr size_t OFF_EO     = OFF_H + (size_t)CAP * ISZ * 2;

__device__ __forceinline__ ushort f2bf(float f) {
    union { float f; unsigned u; } v; v.f = f;
    unsigned u = v.u;
    u += 0x7FFFu + ((u >> 16) & 1u);   // RNE
    return (ushort)(u >> 16);
}

__device__ __forceinline__ bf16x8 cvt_frag(float4 a, float4 b) {
    bf16x8 r;
    r[0] = (short)f2bf(a.x); r[1] = (short)f2bf(a.y);
    r[2] = (short)f2bf(a.z); r[3] = (short)f2bf(a.w);
    r[4] = (short)f2bf(b.x); r[5] = (short)f2bf(b.y);
    r[6] = (short)f2bf(b.z); r[7] = (short)f2bf(b.w);
    return r;
}

// async global -> LDS, 16B per lane. LDS dest: wave-uniform base + lane*16.
__device__ __forceinline__ void gl_lds16(const void* g, void* l) {
    __builtin_amdgcn_global_load_lds(
        (__attribute__((address_space(1))) void*)(unsigned long long)g,
        (__attribute__((address_space(3))) void*)l,
        16, 0, 0);
}

// counted-waitcnt + convergence-visible barrier (8-phase template pattern)
#define WAIT_BARRIER(N)                                                \
    do {                                                               \
        asm volatile("s_waitcnt vmcnt(" #N ") lgkmcnt(0)" ::: "memory"); \
        __builtin_amdgcn_s_barrier();                                  \
    } while (0)

// ---------------- router ----------------
__global__ void router_kernel(const float* __restrict__ x,
                              const float* __restrict__ gw,
                              float* __restrict__ logits_out,
                              int* __restrict__ topk_idx,
                              float* __restrict__ topk_w,
                              int* __restrict__ counts) {
    int gwave = (int)((blockIdx.x * blockDim.x + threadIdx.x) >> 6);
    int lane = threadIdx.x & 63;
    if (gwave >= T_TOKENS) return;
    const float* xr = x + (size_t)gwave * DIM;
    float xv[16];
#pragma unroll
    for (int i = 0; i < 16; i++) xv[i] = xr[i * 64 + lane];
    float lg[8];
#pragma unroll
    for (int e = 0; e < 8; e++) {
        const float* g = gw + e * DIM;
        float s = 0.f;
#pragma unroll
        for (int i = 0; i < 16; i++) s += xv[i] * g[i * 64 + lane];
#pragma unroll
        for (int off = 32; off > 0; off >>= 1) s += __shfl_xor(s, off, 64);
        lg[e] = s;
    }
    if (lane == 0) {
#pragma unroll
        for (int e = 0; e < 8; e++) logits_out[gwave * 8 + e] = lg[e];
        int e0 = 0; float l0 = lg[0];
#pragma unroll
        for (int e = 1; e < 8; e++) if (lg[e] > l0) { l0 = lg[e]; e0 = e; }
        int e1 = -1; float l1 = -1e30f;
#pragma unroll
        for (int e = 0; e < 8; e++) if (e != e0 && lg[e] > l1) { l1 = lg[e]; e1 = e; }
        float w0 = 1.f / (1.f + __expf(l1 - l0));
        float w1 = 1.f - w0;
        topk_idx[gwave * 2] = e0; topk_idx[gwave * 2 + 1] = e1;
        topk_w[gwave * 2] = w0;  topk_w[gwave * 2 + 1] = w1;
        atomicAdd(&counts[e0], 1);
        atomicAdd(&counts[e1], 1);
    }
}

__global__ void scan_kernel(const int* __restrict__ counts, int* __restrict__ offsets,
                            int* __restrict__ tile_e, int* __restrict__ tile_r0,
                            int* __restrict__ tile_nr, int* __restrict__ n_tiles) {
    if (threadIdx.x == 0) {
        int o = 0, nt = 0;
        for (int e = 0; e < NEXP; e++) {
            offsets[e] = o;
            int c = counts[e];
            for (int r = 0; r < c; r += BM) {
                tile_e[nt] = e; tile_r0[nt] = o + r;
                int nr = c - r; if (nr > BM) nr = BM;
                tile_nr[nt] = nr; nt++;
            }
            o += c;
        }
        *n_tiles = nt;
    }
}

__global__ void assign_kernel(const int* __restrict__ topk_idx,
                              const float* __restrict__ topk_w,
                              const int* __restrict__ offsets,
                              int* __restrict__ cursor,
                              int* __restrict__ row_token,
                              float* __restrict__ row_w,
                              int* __restrict__ tok_slot) {
    int t = blockIdx.x * blockDim.x + threadIdx.x;
    if (t >= T_TOKENS) return;
    for (int k = 0; k < 2; k++) {
        int e = topk_idx[t * 2 + k];
        int pos = atomicAdd(&cursor[e], 1);
        int slot = offsets[e] + pos;
        row_token[slot] = t;
        row_w[slot] = topk_w[t * 2 + k];
        tok_slot[t * 2 + k] = slot;
    }
}

__global__ void gather_kernel(const float* __restrict__ x,
                              const int* __restrict__ row_token,
                              ushort* __restrict__ xg) {
    int slot = blockIdx.x;
    int t = row_token[slot];
    const float4* src = (const float4*)(x + (size_t)t * DIM);
    ushort* dst = xg + (size_t)slot * DIM;
    int i = threadIdx.x;
    float4 v = src[i];
    ushort4 o; o.x = f2bf(v.x); o.y = f2bf(v.y); o.z = f2bf(v.z); o.w = f2bf(v.w);
    *(ushort4*)(dst + i * 4) = o;
}

// ---------------- GEMM 1: xg @ (w_gate,w_up)^T + SwiGLU -> h ----------------
// 256 thr = 4 waves (2x2). Tile M=128, N=64 per tensor, BK=32.
// Counted-vmcnt pipeline: raw s_barrier, A-DMA drained per step (vmcnt(4) covers
// exactly the 2 A-DMA issues), fp32 B loads 2 steps deep, never drained mid-loop.
// A LDS: chunk-XOR swizzle via pre-swizzled DMA source. B LDS: 80B padded stride.
__global__ __launch_bounds__(256, 3) void gemm_gu_lds(
    const ushort* __restrict__ xg,
    const float* __restrict__ wg,
    const float* __restrict__ wu,
    const int* __restrict__ tile_e, const int* __restrict__ tile_r0,
    const int* __restrict__ tile_nr,
    ushort* __restrict__ h) {
    // XCD slab grouping: 4 consecutive row-tiles x same col-block -> same XCD.
    int l = blockIdx.x + blockIdx.y * 48;          // 0..1535, hw dispatch order
    int xcd = l & 7, s = l >> 3;                   // s: 0..191
    int slab = xcd * 48 + (s >> 2);                // 0..383
    int tile = (slab >> 5) * 4 + (s & 3);          // 0..47
    int col0 = (slab & 31) * 64;

    int nr = tile_nr[tile];
    if (nr == 0) return;
    int e = tile_e[tile], row0 = tile_r0[tile];

    __shared__ __align__(16) char lds[2 * GU_BUFB];

    int tid = threadIdx.x;
    int lane = tid & 63;
    int wid = tid >> 6;
    int wr = wid >> 1, wc = wid & 1;

    // A DMA: thread tid -> LDS slot (row=tid>>2, chunk=tid&3); source chunk pre-XORed.
    int ar = tid >> 2, ac = tid & 3;
    int akq = ac ^ ((ar >> 1) & 3);
    const ushort* a_src = xg + (size_t)(row0 + ar) * DIM + akq * 8;
    size_t woff = (size_t)wid * 1024;              // wave-uniform LDS byte base

    // B: quad-contiguous fp32 loads (row=tid>>2, chunk=tid&3), padded ds_write.
    const float* g_src = wg + ((size_t)e * ISZ + col0 + ar) * DIM + ac * 8;
    const float* u_src = wu + ((size_t)e * ISZ + col0 + ar) * DIM + ac * 8;
    int bwr = ar * B_STRIDE + ac * 16;

    // read offsets (bytes within one buffer)
    int fr = lane & 15, kq = lane >> 4;
    int aoff[4];
#pragma unroll
    for (int i = 0; i < 4; i++) {
        int row = wr * 64 + i * 16 + fr;
        aoff[i] = row * 64 + ((kq ^ ((row >> 1) & 3)) << 4);
    }
    int go[2], uo[2];
#pragma unroll
    for (int j = 0; j < 2; j++) {
        int rowb = wc * 32 + j * 16 + fr;
        go[j] = A_BYTES + rowb * B_STRIDE + kq * 16;
        uo[j] = A_BYTES + B_BYTES + rowb * B_STRIDE + kq * 16;
    }

    f32x4 accG[4][2] = {};
    f32x4 accU[4][2] = {};

    float4 g0a, g0b, u0a, u0b;    // set0: data for even iters
    float4 g1a, g1b, u1a, u1b;    // set1: data for odd iters

    auto stageA = [&](int b, int k) {
        char* lb = lds + b * GU_BUFB;
        gl_lds16(a_src + k, lb + woff);
        gl_lds16(a_src + (size_t)64 * DIM + k, lb + woff + 4096);
    };

    // prologue
    g0a = *(const float4*)(g_src); g0b = *(const float4*)(g_src + 4);
    u0a = *(const float4*)(u_src); u0b = *(const float4*)(u_src + 4);
    stageA(0, 0);
    g1a = *(const float4*)(g_src + BK); g1b = *(const float4*)(g_src + BK + 4);
    u1a = *(const float4*)(u_src + BK); u1b = *(const float4*)(u_src + BK + 4);
    {
        char* lb = lds;
        *(bf16x8*)(lb + A_BYTES + bwr) = cvt_frag(g0a, g0b);
        *(bf16x8*)(lb + A_BYTES + B_BYTES + bwr) = cvt_frag(u0a, u0b);
    }
    WAIT_BARRIER(0);

    auto substep = [&](int it, int p,
                       float4& wg0, float4& wg1, float4& wu0, float4& wu1,   // write set (iter it+1)
                       float4& lg0, float4& lg1, float4& lu0, float4& lu1) { // load set (iter it+2)
        const char* lb = lds + p * GU_BUFB;
        bf16x8 A[4], Bg[2], Bu[2];
#pragma unroll
        for (int i = 0; i < 4; i++) A[i] = *(const bf16x8*)(lb + aoff[i]);
#pragma unroll
        for (int j = 0; j < 2; j++) {
            Bg[j] = *(const bf16x8*)(lb + go[j]);
            Bu[j] = *(const bf16x8*)(lb + uo[j]);
        }
        if (it + 1 < GU_NSTEP) stageA(p ^ 1, (it + 1) * BK);
        asm volatile("" ::: "memory");             // pin A-DMA before B loads in vm queue
        if (it + 2 < GU_NSTEP) {
            int k2 = (it + 2) * BK;
            lg0 = *(const float4*)(g_src + k2); lg1 = *(const float4*)(g_src + k2 + 4);
            lu0 = *(const float4*)(u_src + k2); lu1 = *(const float4*)(u_src + k2 + 4);
        }
#pragma unroll
        for (int i = 0; i < 4; i++)
#pragma unroll
            for (int j = 0; j < 2; j++) {
                accG[i][j] = __builtin_amdgcn_mfma_f32_16x16x32_bf16(A[i], Bg[j], accG[i][j], 0, 0, 0);
                accU[i][j] = __builtin_amdgcn_mfma_f32_16x16x32_bf16(A[i], Bu[j], accU[i][j], 0, 0, 0);
            }
        if (it + 1 < GU_NSTEP) {
            char* wb = lds + (p ^ 1) * GU_BUFB;
            *(bf16x8*)(wb + A_BYTES + bwr) = cvt_frag(wg0, wg1);
            *(bf16x8*)(wb + A_BYTES + B_BYTES + bwr) = cvt_frag(wu0, wu1);
            if (it + 2 < GU_NSTEP) WAIT_BARRIER(4);
            else                   WAIT_BARRIER(0);
        }
    };

    for (int it = 0; it < GU_NSTEP; it += 2) {
        substep(it,     0, g1a, g1b, u1a, u1b, g0a, g0b, u0a, u0b);
        substep(it + 1, 1, g0a, g0b, u0a, u0b, g1a, g1b, u1a, u1b);
    }

    int q = lane >> 4;
#pragma unroll
    for (int i = 0; i < 4; i++) {
#pragma unroll
        for (int r = 0; r < 4; r++) {
            int lrow = wr * 64 + i * 16 + q * 4 + r;
            if (lrow < nr) {
#pragma unroll
                for (int j = 0; j < 2; j++) {
                    float g = accG[i][j][r], u = accU[i][j][r];
                    float hv = g / (1.f + __expf(-g)) * u;
                    h[(size_t)(row0 + lrow) * ISZ + col0 + wc * 32 + j * 16 + fr] = f2bf(hv);
                }
            }
        }
    }
}

// ---------------- GEMM 2: h @ w_down^T -> eo (plain stores) ----------------
__global__ __launch_bounds__(256, 3) void gemm_down_lds(
    const ushort* __restrict__ h,
    const float* __restrict__ wd,
    const int* __restrict__ tile_e, const int* __restrict__ tile_r0,
    const int* __restrict__ tile_nr,
    float* __restrict__ eo) {
    int l = blockIdx.x + blockIdx.y * 48;          // 0..767
    int xcd = l & 7, s = l >> 3;                   // s: 0..95
    int slab = xcd * 24 + (s >> 2);                // 0..191
    int tile = (slab >> 4) * 4 + (s & 3);          // 0..47
    int col0 = (slab & 15) * 64;

    int nr = tile_nr[tile];
    if (nr == 0) return;
    int e = tile_e[tile], row0 = tile_r0[tile];

    __shared__ __align__(16) char lds[2 * DN_BUFB];

    int tid = threadIdx.x;
    int lane = tid & 63;
    int wid = tid >> 6;
    int wr = wid >> 1, wc = wid & 1;

    int ar = tid >> 2, ac = tid & 3;
    int akq = ac ^ ((ar >> 1) & 3);
    const ushort* a_src = h + (size_t)(row0 + ar) * ISZ + akq * 8;
    size_t woff = (size_t)wid * 1024;

    const float* b_src = wd + ((size_t)e * DIM + col0 + ar) * ISZ + ac * 8;
    int bwr = ar * B_STRIDE + ac * 16;

    int fr = lane & 15, kq = lane >> 4;
    int aoff[4];
#pragma unroll
    for (int i = 0; i < 4; i++) {
        int row = wr * 64 + i * 16 + fr;
        aoff[i] = row * 64 + ((kq ^ ((row >> 1) & 3)) << 4);
    }
    int bo[2];
#pragma unroll
    for (int j = 0; j < 2; j++) {
        int rowb = wc * 32 + j * 16 + fr;
        bo[j] = A_BYTES + rowb * B_STRIDE + kq * 16;
    }

    f32x4 acc[4][2] = {};
    float4 b0a, b0b, b1a, b1b;

    auto stageA = [&](int b, int k) {
        char* lb = lds + b * DN_BUFB;
        gl_lds16(a_src + k, lb + woff);
        gl_lds16(a_src + (size_t)64 * ISZ + k, lb + woff + 4096);
    };

    b0a = *(const float4*)(b_src); b0b = *(const float4*)(b_src + 4);
    stageA(0, 0);
    b1a = *(const float4*)(b_src + BK); b1b = *(const float4*)(b_src + BK + 4);
    *(bf16x8*)(lds + A_BYTES + bwr) = cvt_frag(b0a, b0b);
    WAIT_BARRIER(0);

    auto substep = [&](int it, int p,
                       float4& wb0, float4& wb1, float4& lb0, float4& lb1) {
        const char* lb = lds + p * DN_BUFB;
        bf16x8 A[4], Bf[2];
#pragma unroll
        for (int i = 0; i < 4; i++) A[i] = *(const bf16x8*)(lb + aoff[i]);
#pragma unroll
        for (int j = 0; j < 2; j++) Bf[j] = *(const bf16x8*)(lb + bo[j]);
        if (it + 1 < DN_NSTEP) stageA(p ^ 1, (it + 1) * BK);
        asm volatile("" ::: "memory");
        if (it + 2 < DN_NSTEP) {
            int k2 = (it + 2) * BK;
            lb0 = *(const float4*)(b_src + k2); lb1 = *(const float4*)(b_src + k2 + 4);
        }
#pragma unroll
        for (int i = 0; i < 4; i++)
#pragma unroll
            for (int j = 0; j < 2; j++)
                acc[i][j] = __builtin_amdgcn_mfma_f32_16x16x32_bf16(A[i], Bf[j], acc[i][j], 0, 0, 0);
        if (it + 1 < DN_NSTEP) {
            char* wbuf = lds + (p ^ 1) * DN_BUFB;
            *(bf16x8*)(wbuf + A_BYTES + bwr) = cvt_frag(wb0, wb1);
            if (it + 2 < DN_NSTEP) WAIT_BARRIER(2);
            else                   WAIT_BARRIER(0);
        }
    };

    for (int it = 0; it < DN_NSTEP; it += 2) {
        substep(it,     0, b1a, b1b, b0a, b0b);
        substep(it + 1, 1, b0a, b0b, b1a, b1b);
    }

    int q = lane >> 4;
#pragma unroll
    for (int i = 0; i < 4; i++) {
#pragma unroll
        for (int r = 0; r < 4; r++) {
            int lrow = wr * 64 + i * 16 + q * 4 + r;
            if (lrow < nr) {
                int slot = row0 + lrow;
#pragma unroll
                for (int j = 0; j < 2; j++) {
                    int col = col0 + wc * 32 + j * 16 + fr;
                    eo[(size_t)slot * DIM + col] = acc[i][j][r];
                }
            }
        }
    }
}

// ---------------- combine: out[t] = w0*eo[s0] + w1*eo[s1] ----------------
__global__ __launch_bounds__(256) void combine_kernel(const float* __restrict__ eo,
                                                      const int* __restrict__ tok_slot,
                                                      const float* __restrict__ row_w,
                                                      float* __restrict__ out) {
    int t = blockIdx.x;
    int c = threadIdx.x * 4;
    int s0 = tok_slot[t * 2], s1 = tok_slot[t * 2 + 1];
    float w0 = row_w[s0], w1 = row_w[s1];
    float4 a = *(const float4*)(eo + (size_t)s0 * DIM + c);
    float4 b = *(const float4*)(eo + (size_t)s1 * DIM + c);
    float4 o;
    o.x = w0 * a.x + w1 * b.x;
    o.y = w0 * a.y + w1 * b.y;
    o.z = w0 * a.z + w1 * b.z;
    o.w = w0 * a.w + w1 * b.w;
    *(float4*)(out + (size_t)t * DIM + c) = o;
}

extern "C" void kernel_launch(void* const* d_in, const int* in_sizes, int n_in,
                              void* d_out, int out_size, void* d_ws, size_t ws_size,
                              hipStream_t stream) {
    const float* x      = (const float*)d_in[0];
    const float* gate_w = (const float*)d_in[1];
    const float* w_gate = (const float*)d_in[2];
    const float* w_up   = (const float*)d_in[3];
    const float* w_down = (const float*)d_in[4];

    float* out = (float*)d_out;
    float* logits_out = out + (size_t)T_TOKENS * DIM;

    char* ws = (char*)d_ws;
    int*    counts    = (int*)(ws + OFF_COUNTS);
    int*    cursor    = (int*)(ws + OFF_CURSOR);
    int*    offsets   = (int*)(ws + OFF_OFFSETS);
    int*    n_tiles   = (int*)(ws + OFF_NTILES);
    int*    tile_e    = (int*)(ws + OFF_TILE_E);
    int*    tile_r0   = (int*)(ws + OFF_TILE_R0);
    int*    tile_nr   = (int*)(ws + OFF_TILE_NR);
    int*    topk_idx  = (int*)(ws + OFF_TOPK_I);
    float*  topk_w    = (float*)(ws + OFF_TOPK_W);
    int*    row_token = (int*)(ws + OFF_ROW_T);
    float*  row_w     = (float*)(ws + OFF_ROW_W);
    int*    tok_slot  = (int*)(ws + OFF_TSLOT);
    ushort* xg        = (ushort*)(ws + OFF_XG);
    ushort* h         = (ushort*)(ws + OFF_H);
    float*  eo        = (float*)(ws + OFF_EO);

    hipMemsetAsync(d_ws, 0, 1024, stream);

    router_kernel<<<T_TOKENS / 4, 256, 0, stream>>>(x, gate_w, logits_out, topk_idx, topk_w, counts);
    scan_kernel<<<1, 64, 0, stream>>>(counts, offsets, tile_e, tile_r0, tile_nr, n_tiles);
    assign_kernel<<<T_TOKENS / 256, 256, 0, stream>>>(topk_idx, topk_w, offsets, cursor,
                                                      row_token, row_w, tok_slot);
    gather_kernel<<<NPAIRS, 256, 0, stream>>>(x, row_token, xg);

    dim3 g1(48, ISZ / 64);            // 48 x 32
    gemm_gu_lds<<<g1, 256, 0, stream>>>(xg, w_gate, w_up, tile_e, tile_r0, tile_nr, h);
    dim3 g2(48, DIM / 64);            // 48 x 16
    gemm_down_lds<<<g2, 256, 0, stream>>>(h, w_down, tile_e, tile_r0, tile_nr, eo);
    combine_kernel<<<T_TOKENS, 256, 0, stream>>>(eo, tok_slot, row_w, out);
}